// Round 2
// baseline (4772.804 us; speedup 1.0000x reference)
//
#include <hip/hip_runtime.h>
#include <math.h>

// ---------------- compile-time problem constants ----------------
#define TOTE 5400000   // total edges
#define TOTN 234000    // total node rows (all types concatenated)
#define TOTC 514000    // total dst-counter slots over 14 edge types
#define HID  128

// Workspace budget note: d_ws usage kept at ~245.8 MB (h + acc + 3 CSR meta arrays).
// col (21.6 MB) + per-round agg (<=37.9 MB) live in d_out (71.7 MB), which is
// scratch until the final head GEMM overwrites all of it.

__constant__ int c_EPRE[15]   = {0,1000000,2000000,2500000,3000000,3200000,3400000,3600000,3800000,3900000,4000000,4300000,4600000,5000000,5400000};
__constant__ int c_ECNT[14]   = {1000000,1000000,500000,500000,200000,200000,200000,200000,100000,100000,300000,300000,400000,400000};
__constant__ int c_CNTOFF[14] = {0,40000,140000,143000,183000,203000,243000,263000,303000,311000,351000,411000,451000,454000};
__constant__ int c_CNTN[14]   = {40000,100000,3000,40000,20000,40000,20000,40000,8000,40000,60000,40000,3000,60000};
__constant__ int c_SRCOFF[14] = {0,100000,100000,140000,100000,143000,100000,143000,100000,163000,100000,171000,171000,231000};
__constant__ int c_NODEPRE[8] = {0,100000,140000,143000,163000,171000,231000,234000};
__constant__ float c_INVND[7] = {1.0f, 1.0f/6.0f, 1.0f, 0.5f, 1.0f, 0.5f, 1.0f};

struct EdgeArgs { const int* ei[14]; };

// ---------------- CSR build ----------------
__global__ __launch_bounds__(256) void count_k(EdgeArgs a, int* __restrict__ cnt) {
    int g = blockIdx.x * 256 + threadIdx.x;
    if (g >= TOTE) return;
    int e = 0;
    while (g >= c_EPRE[e + 1]) e++;
    int k = g - c_EPRE[e];
    int dst = a.ei[e][c_ECNT[e] + k];
    atomicAdd(&cnt[c_CNTOFF[e] + dst], 1);
}

__global__ __launch_bounds__(1024) void scan_k(const int* __restrict__ cnt,
                                               int* __restrict__ cursor, float* __restrict__ inv_deg) {
    int e = blockIdx.x;
    int n = c_CNTN[e];
    int base = c_CNTOFF[e];
    int gbase = c_EPRE[e];
    int t = threadIdx.x;
    int lane = t & 63;
    int w = t >> 6;
    __shared__ int wtot[16];
    __shared__ int chunkTot;
    int carry = 0;
    for (int start = 0; start < n; start += 1024) {
        int idx = start + t;
        int v = (idx < n) ? cnt[base + idx] : 0;
        int incl = v;
        #pragma unroll
        for (int d = 1; d < 64; d <<= 1) {
            int o = __shfl_up(incl, d);
            if (lane >= d) incl += o;
        }
        if (lane == 63) wtot[w] = incl;
        __syncthreads();
        if (t < 16) {
            int x = wtot[t];
            int ix = x;
            #pragma unroll
            for (int d = 1; d < 16; d <<= 1) {
                int o = __shfl_up(ix, d);
                if (t >= d) ix += o;
            }
            wtot[t] = ix - x;           // exclusive wave offset
            if (t == 15) chunkTot = ix; // chunk total
        }
        __syncthreads();
        int excl = incl - v + wtot[w] + carry;
        if (idx < n) {
            cursor[base + idx]  = gbase + excl;
            inv_deg[base + idx] = 1.0f / fmaxf((float)v, 1.0f);
        }
        carry += chunkTot;
        __syncthreads();
    }
}

__global__ __launch_bounds__(256) void fill_k(EdgeArgs a, int* __restrict__ cursor, int* __restrict__ col) {
    int g = blockIdx.x * 256 + threadIdx.x;
    if (g >= TOTE) return;
    int e = 0;
    while (g >= c_EPRE[e + 1]) e++;
    int k = g - c_EPRE[e];
    int src = a.ei[e][k];
    int dst = a.ei[e][c_ECNT[e] + k];
    int pos = atomicAdd(&cursor[c_CNTOFF[e] + dst], 1);
    col[pos] = c_SRCOFF[e] + src;   // pre-offset to global node row
}

// ---------------- aggregation (mean over neighbors), one wave per dst row ----------------
// After fill_k, cursor[i] == row_start[i] + cnt[i]  =>  row_start = cursor - cnt.
struct AggArgs { int nSlots; int blockPrefix[9]; int cntOff[8]; int aggOff[8]; int rowsN[8]; };

__global__ __launch_bounds__(256) void agg_k(AggArgs a,
        const int* __restrict__ cnt, const int* __restrict__ cursor,
        const float* __restrict__ inv_deg, const int* __restrict__ col,
        const float* __restrict__ h, float* __restrict__ agg) {
    int b = blockIdx.x;
    int s = 0;
    while (b >= a.blockPrefix[s + 1]) s++;
    int row = (b - a.blockPrefix[s]) * 4 + (threadIdx.x >> 6);
    if (row >= a.rowsN[s]) return;
    int lane = threadIdx.x & 63;
    int base = a.cntOff[s] + row;
    int nn = cnt[base];
    int rs = cursor[base] - nn;
    float inv = inv_deg[base];
    const int* cp = col + rs;
    float v0 = 0.f, v1 = 0.f;
    int j = 0;
    for (; j + 4 <= nn; j += 4) {
        int c0 = cp[j] * HID, c1 = cp[j+1] * HID, c2 = cp[j+2] * HID, c3 = cp[j+3] * HID;
        float a0 = h[c0 + lane],      a1 = h[c1 + lane],      a2 = h[c2 + lane],      a3 = h[c3 + lane];
        float b0 = h[c0 + 64 + lane], b1 = h[c1 + 64 + lane], b2 = h[c2 + 64 + lane], b3 = h[c3 + 64 + lane];
        v0 += (a0 + a1) + (a2 + a3);
        v1 += (b0 + b1) + (b2 + b3);
    }
    for (; j < nn; j++) {
        int c = cp[j] * HID;
        v0 += h[c + lane];
        v1 += h[c + 64 + lane];
    }
    float* op = agg + (size_t)(a.aggOff[s] + row) * HID;
    op[lane]      = v0 * inv;
    op[lane + 64] = v1 * inv;
}

// ---------------- fused GEMM: out = A1@W1^T (+ A2@W2^T) + bias, optional row-l2norm, write/accum ----------------
// MODE 0: plain write (input projection). MODE 1: l2norm then write. MODE 2: l2norm then +=.
struct GemmArgs {
    int nSlots; int blockPrefix[9];
    const float* A1[8]; const float* A2[8];
    const float* W1[8]; const float* W2[8];
    const float* bias[8]; float* out[8];
    int rows[8];
};

#define KB 32

template<int MODE, bool TWO>
__global__ __launch_bounds__(256) void gemm_k(GemmArgs g) {
    __shared__ float As[KB][68];    // [k][row], padded
    __shared__ float Ws[KB][132];   // [k][col]
    int b = blockIdx.x;
    int s = 0;
    while (b >= g.blockPrefix[s + 1]) s++;
    int rows = g.rows[s];
    int row0 = (b - g.blockPrefix[s]) * 64;
    int t = threadIdx.x;
    int tc = t & 31;        // col group: cols tc, tc+32, tc+64, tc+96
    int tr = t >> 5;        // row group: rows tr*8 .. tr*8+7
    float acc[8][4];
    #pragma unroll
    for (int i = 0; i < 8; i++)
        #pragma unroll
        for (int j = 0; j < 4; j++) acc[i][j] = 0.f;

    const int MM = TWO ? 2 : 1;
    for (int m = 0; m < MM; m++) {
        const float* __restrict__ A = m ? g.A2[s] : g.A1[s];
        const float* __restrict__ W = m ? g.W2[s] : g.W1[s];
        for (int k0 = 0; k0 < HID; k0 += KB) {
            __syncthreads();
            // A tile: 64 rows x 32 k  (512 float4s)
            #pragma unroll
            for (int i = 0; i < 2; i++) {
                int idx = t + i * 256;
                int row = idx >> 3, k4 = idx & 7;
                float4 v = make_float4(0.f, 0.f, 0.f, 0.f);
                if (row0 + row < rows)
                    v = *(const float4*)&A[(size_t)(row0 + row) * HID + k0 + k4 * 4];
                As[k4*4+0][row] = v.x; As[k4*4+1][row] = v.y;
                As[k4*4+2][row] = v.z; As[k4*4+3][row] = v.w;
            }
            // W tile: 128 cols x 32 k (1024 float4s); W layout [c][k]
            #pragma unroll
            for (int i = 0; i < 4; i++) {
                int idx = t + i * 256;
                int c = idx >> 3, k4 = idx & 7;
                float4 v = *(const float4*)&W[(size_t)c * HID + k0 + k4 * 4];
                Ws[k4*4+0][c] = v.x; Ws[k4*4+1][c] = v.y;
                Ws[k4*4+2][c] = v.z; Ws[k4*4+3][c] = v.w;
            }
            __syncthreads();
            #pragma unroll
            for (int k = 0; k < KB; k++) {
                float4 a0 = *(const float4*)&As[k][tr * 8];
                float4 a1 = *(const float4*)&As[k][tr * 8 + 4];
                float w0 = Ws[k][tc], w1 = Ws[k][tc + 32], w2 = Ws[k][tc + 64], w3 = Ws[k][tc + 96];
                float av[8] = {a0.x, a0.y, a0.z, a0.w, a1.x, a1.y, a1.z, a1.w};
                #pragma unroll
                for (int i = 0; i < 8; i++) {
                    acc[i][0] += av[i] * w0;
                    acc[i][1] += av[i] * w1;
                    acc[i][2] += av[i] * w2;
                    acc[i][3] += av[i] * w3;
                }
            }
        }
    }

    const float* bias = g.bias[s];
    float bsv[4] = {bias[tc], bias[tc + 32], bias[tc + 64], bias[tc + 96]};
    #pragma unroll
    for (int i = 0; i < 8; i++)
        #pragma unroll
        for (int j = 0; j < 4; j++) acc[i][j] += bsv[j];

    if (MODE != 0) {
        #pragma unroll
        for (int i = 0; i < 8; i++) {
            float ss = acc[i][0]*acc[i][0] + acc[i][1]*acc[i][1] + acc[i][2]*acc[i][2] + acc[i][3]*acc[i][3];
            ss += __shfl_xor(ss, 1);
            ss += __shfl_xor(ss, 2);
            ss += __shfl_xor(ss, 4);
            ss += __shfl_xor(ss, 8);
            ss += __shfl_xor(ss, 16);
            float scale = 1.0f / fmaxf(sqrtf(ss), 1e-12f);
            #pragma unroll
            for (int j = 0; j < 4; j++) acc[i][j] *= scale;
        }
    }

    float* out = g.out[s];
    #pragma unroll
    for (int i = 0; i < 8; i++) {
        int r = row0 + tr * 8 + i;
        if (r < rows) {
            float* o = out + (size_t)r * HID;
            #pragma unroll
            for (int j = 0; j < 4; j++) {
                if (MODE == 2) o[tc + 32 * j] += acc[i][j];
                else           o[tc + 32 * j]  = acc[i][j];
            }
        }
    }
}

// ---------------- per-layer update: h = relu(LN(acc/numdst + h)), in-place; one wave per row ----------------
__global__ __launch_bounds__(256) void update_k(float* __restrict__ h, const float* __restrict__ acc,
                                                const float* __restrict__ ln_g, const float* __restrict__ ln_b, int l) {
    int row = blockIdx.x * 4 + (threadIdx.x >> 6);
    if (row >= TOTN) return;
    int lane = threadIdx.x & 63;
    int t = 0;
    while (row >= c_NODEPRE[t + 1]) t++;
    float invnd = c_INVND[t];
    const float* gg = ln_g + ((size_t)l * 7 + t) * HID;
    const float* bb = ln_b + ((size_t)l * 7 + t) * HID;
    float* hp = h + (size_t)row * HID;
    const float* ap = acc + (size_t)row * HID;
    float x0 = ap[lane] * invnd + hp[lane];
    float x1 = ap[lane + 64] * invnd + hp[lane + 64];
    float s = x0 + x1;
    s += __shfl_xor(s, 1);  s += __shfl_xor(s, 2);  s += __shfl_xor(s, 4);
    s += __shfl_xor(s, 8);  s += __shfl_xor(s, 16); s += __shfl_xor(s, 32);
    float mean = s * (1.0f / 128.0f);
    float d0 = x0 - mean, d1 = x1 - mean;
    float vs = d0 * d0 + d1 * d1;
    vs += __shfl_xor(vs, 1);  vs += __shfl_xor(vs, 2);  vs += __shfl_xor(vs, 4);
    vs += __shfl_xor(vs, 8);  vs += __shfl_xor(vs, 16); vs += __shfl_xor(vs, 32);
    float rstd = rsqrtf(vs * (1.0f / 128.0f) + 1e-5f);
    float y0 = d0 * rstd * gg[lane]      + bb[lane];
    float y1 = d1 * rstd * gg[lane + 64] + bb[lane + 64];
    hp[lane]      = fmaxf(y0, 0.f);
    hp[lane + 64] = fmaxf(y1, 0.f);
}

// ---------------- host ----------------
extern "C" void kernel_launch(void* const* d_in, const int* in_sizes, int n_in,
                              void* d_out, int out_size, void* d_ws, size_t ws_size,
                              hipStream_t stream) {
    (void)in_sizes; (void)n_in; (void)out_size; (void)ws_size;
    const float* Wp   = (const float*)d_in[21];
    const float* bp   = (const float*)d_in[22];
    const float* Wl   = (const float*)d_in[23];
    const float* bl   = (const float*)d_in[24];
    const float* Wr   = (const float*)d_in[25];
    const float* ln_g = (const float*)d_in[26];
    const float* ln_b = (const float*)d_in[27];
    const float* Wu   = (const float*)d_in[28];
    const float* bu   = (const float*)d_in[29];
    const float* Wv   = (const float*)d_in[30];
    const float* bv   = (const float*)d_in[31];
    float* out = (float*)d_out;

    // d_ws carve: 245.8 MB total
    float* h      = (float*)d_ws;                                 // TOTN*128 floats
    float* acc    = h + (size_t)TOTN * HID;                       // TOTN*128 floats
    int*   cnt    = (int*)(acc + (size_t)TOTN * HID);             // TOTC ints
    int*   cursor = cnt + TOTC;                                   // TOTC ints
    float* invdeg = (float*)(cursor + TOTC);                      // TOTC floats

    // d_out carve (scratch until final head GEMM overwrites all 17.92M floats):
    int*   col = (int*)d_out;                                     // TOTE ints (21.6 MB)
    float* agg = (float*)d_out + TOTE;                            // up to 74000*128 floats (37.9 MB)

    static const int CNTOFF[14] = {0,40000,140000,143000,183000,203000,243000,263000,303000,311000,351000,411000,451000,454000};
    static const int DSTOFF[14] = {100000,0,140000,100000,143000,100000,143000,100000,163000,100000,171000,100000,231000,171000};
    static const int NODEPRE[8] = {0,100000,140000,143000,163000,171000,231000,234000};
    static const int NT[7]      = {100000,40000,3000,20000,8000,60000,3000};

    // Rounds: <=1 edge type per dst type per round, <=74000 agg rows per round.
    // MODE1 rounds (write) cover every dst type's full row range before any MODE2 (+=).
    static const int RN[10]    = {1,1,5,1,2,1,1,1,1,1};
    static const int RM[10]    = {1,1,1,1,2,2,2,2,2,2};
    static const int RE[10][5] = {{1,0,0,0,0},{1,0,0,0,0},{0,2,4,8,12},{10,0,0,0,0},{3,6,0,0,0},{13,0,0,0,0},{5,0,0,0,0},{7,0,0,0,0},{9,0,0,0,0},{11,0,0,0,0}};
    static const int RB[10][5] = {{0,0,0,0,0},{50000,0,0,0,0},{0,0,0,0,0},{0,0,0,0,0},{0,0,0,0,0},{0,0,0,0,0},{0,0,0,0,0},{0,0,0,0,0},{0,0,0,0,0},{0,0,0,0,0}};
    static const int RR[10][5] = {{50000,0,0,0,0},{50000,0,0,0,0},{40000,3000,20000,8000,3000},{60000,0,0,0,0},{40000,20000,0,0,0},{60000,0,0,0,0},{40000,0,0,0,0},{40000,0,0,0,0},{40000,0,0,0,0},{40000,0,0,0,0}};

    EdgeArgs ea;
    for (int e = 0; e < 14; e++) ea.ei[e] = (const int*)d_in[7 + e];

    hipMemsetAsync(cnt, 0, TOTC * sizeof(int), stream);
    count_k<<<(TOTE + 255) / 256, 256, 0, stream>>>(ea, cnt);
    scan_k<<<14, 1024, 0, stream>>>(cnt, cursor, invdeg);
    fill_k<<<(TOTE + 255) / 256, 256, 0, stream>>>(ea, cursor, col);

    // input projection: h[t] = x[t] @ Wp[t]^T + bp[t]
    {
        GemmArgs ga; ga.nSlots = 7;
        int pre = 0; ga.blockPrefix[0] = 0;
        for (int t = 0; t < 7; t++) {
            ga.A1[t] = (const float*)d_in[t];
            ga.A2[t] = nullptr;
            ga.W1[t] = Wp + (size_t)t * 16384;
            ga.W2[t] = nullptr;
            ga.bias[t] = bp + (size_t)t * HID;
            ga.out[t] = h + (size_t)NODEPRE[t] * HID;
            ga.rows[t] = NT[t];
            pre += (NT[t] + 63) / 64;
            ga.blockPrefix[t + 1] = pre;
        }
        ga.blockPrefix[8] = pre;
        gemm_k<0, false><<<pre, 256, 0, stream>>>(ga);
    }

    for (int l = 0; l < 3; l++) {
        for (int r = 0; r < 10; r++) {
            int ns = RN[r];
            AggArgs aa; aa.nSlots = ns;
            GemmArgs ga; ga.nSlots = ns;
            int apre = 0, gpre = 0, aggRows = 0;
            aa.blockPrefix[0] = 0; ga.blockPrefix[0] = 0;
            for (int s = 0; s < ns; s++) {
                int e  = RE[r][s];
                int rb = RB[r][s];
                int nr = RR[r][s];
                aa.cntOff[s] = CNTOFF[e] + rb;
                aa.aggOff[s] = aggRows;
                aa.rowsN[s]  = nr;
                apre += (nr + 3) / 4;  aa.blockPrefix[s + 1] = apre;
                ga.A1[s]  = agg + (size_t)aggRows * HID;
                ga.A2[s]  = h + (size_t)(DSTOFF[e] + rb) * HID;
                ga.W1[s]  = Wl + ((size_t)l * 14 + e) * 16384;
                ga.W2[s]  = Wr + ((size_t)l * 14 + e) * 16384;
                ga.bias[s]= bl + ((size_t)l * 14 + e) * HID;
                ga.out[s] = acc + (size_t)(DSTOFF[e] + rb) * HID;
                ga.rows[s]= nr;
                gpre += (nr + 63) / 64; ga.blockPrefix[s + 1] = gpre;
                aggRows += nr;
            }
            for (int s = ns; s < 8; s++) { aa.blockPrefix[s + 1] = apre; ga.blockPrefix[s + 1] = gpre; }
            agg_k<<<apre, 256, 0, stream>>>(aa, cnt, cursor, invdeg, col, h, agg);
            if (RM[r] == 1) gemm_k<1, true><<<gpre, 256, 0, stream>>>(ga);
            else            gemm_k<2, true><<<gpre, 256, 0, stream>>>(ga);
        }
        update_k<<<(TOTN + 3) / 4, 256, 0, stream>>>(h, acc, ln_g, ln_b, l);
    }

    // heads: user_emb = l2norm(h_user @ Wu^T + bu), vn_emb = l2norm(h_vn @ Wv^T + bv)
    // (overwrites the col/agg scratch living in d_out; write-only w.r.t. d_out)
    {
        GemmArgs ga; ga.nSlots = 2;
        ga.blockPrefix[0] = 0;
        ga.A1[0] = h;                        ga.A2[0] = nullptr;
        ga.W1[0] = Wu;                       ga.W2[0] = nullptr;
        ga.bias[0] = bu;                     ga.out[0] = out;
        ga.rows[0] = 100000;
        ga.blockPrefix[1] = (100000 + 63) / 64;
        ga.A1[1] = h + (size_t)100000 * HID; ga.A2[1] = nullptr;
        ga.W1[1] = Wv;                       ga.W2[1] = nullptr;
        ga.bias[1] = bv;                     ga.out[1] = out + (size_t)100000 * HID;
        ga.rows[1] = 40000;
        int tot = ga.blockPrefix[1] + (40000 + 63) / 64;
        for (int s = 2; s <= 8; s++) ga.blockPrefix[s] = tot;
        gemm_k<1, false><<<tot, 256, 0, stream>>>(ga);
    }
}

// Round 3
// 2503.521 us; speedup vs baseline: 1.9064x; 1.9064x over previous
//
#include <hip/hip_runtime.h>
#include <math.h>

// ---------------- compile-time problem constants ----------------
#define TOTE 5400000   // total edges
#define TOTN 234000    // total node rows (all types concatenated)
#define TOTC 514000    // total dst-counter slots over 14 edge types
#define HID  128

// ws budget: acc(119.8MB) + h_bf(59.9MB) + w_bf(3.05MB) + cnt/cursor/invdeg(6.2MB) = 189 MB
// (proven-safe ceiling is 245.8 MB; 389 MB crashed in round 1).
// d_out doubles as scratch: col (21.6MB) + agg_bf (18.9MB) = 40.5MB < 71.7MB, overwritten by head GEMM.

typedef __attribute__((ext_vector_type(8))) short short8;
typedef __attribute__((ext_vector_type(8))) __bf16 bf16x8;
typedef __attribute__((ext_vector_type(4))) float floatx4;

__constant__ int c_EPRE[15]   = {0,1000000,2000000,2500000,3000000,3200000,3400000,3600000,3800000,3900000,4000000,4300000,4600000,5000000,5400000};
__constant__ int c_ECNT[14]   = {1000000,1000000,500000,500000,200000,200000,200000,200000,100000,100000,300000,300000,400000,400000};
__constant__ int c_CNTOFF[14] = {0,40000,140000,143000,183000,203000,243000,263000,303000,311000,351000,411000,451000,454000};
__constant__ int c_CNTN[14]   = {40000,100000,3000,40000,20000,40000,20000,40000,8000,40000,60000,40000,3000,60000};
__constant__ int c_SRCOFF[14] = {0,100000,100000,140000,100000,143000,100000,143000,100000,163000,100000,171000,171000,231000};
__constant__ int c_NODEPRE[8] = {0,100000,140000,143000,163000,171000,231000,234000};
__constant__ float c_INVND[7] = {1.0f, 1.0f/6.0f, 1.0f, 0.5f, 1.0f, 0.5f, 1.0f};

static __device__ __forceinline__ unsigned short f2bf(float f) {
    unsigned u = __float_as_uint(f);
    u = u + 0x7FFFu + ((u >> 16) & 1u);
    return (unsigned short)(u >> 16);
}
static __device__ __forceinline__ float bf2f(unsigned short s) {
    return __uint_as_float(((unsigned)s) << 16);
}

struct EdgeArgs { const int* ei[14]; };

// ---------------- CSR build ----------------
__global__ __launch_bounds__(256) void count_k(EdgeArgs a, int* __restrict__ cnt) {
    int g = blockIdx.x * 256 + threadIdx.x;
    if (g >= TOTE) return;
    int e = 0;
    while (g >= c_EPRE[e + 1]) e++;
    int k = g - c_EPRE[e];
    int dst = a.ei[e][c_ECNT[e] + k];
    atomicAdd(&cnt[c_CNTOFF[e] + dst], 1);
}

__global__ __launch_bounds__(1024) void scan_k(const int* __restrict__ cnt,
                                               int* __restrict__ cursor, float* __restrict__ inv_deg) {
    int e = blockIdx.x;
    int n = c_CNTN[e];
    int base = c_CNTOFF[e];
    int gbase = c_EPRE[e];
    int t = threadIdx.x;
    int lane = t & 63;
    int w = t >> 6;
    __shared__ int wtot[16];
    __shared__ int chunkTot;
    int carry = 0;
    for (int start = 0; start < n; start += 1024) {
        int idx = start + t;
        int v = (idx < n) ? cnt[base + idx] : 0;
        int incl = v;
        #pragma unroll
        for (int d = 1; d < 64; d <<= 1) {
            int o = __shfl_up(incl, d);
            if (lane >= d) incl += o;
        }
        if (lane == 63) wtot[w] = incl;
        __syncthreads();
        if (t < 16) {
            int x = wtot[t];
            int ix = x;
            #pragma unroll
            for (int d = 1; d < 16; d <<= 1) {
                int o = __shfl_up(ix, d);
                if (t >= d) ix += o;
            }
            wtot[t] = ix - x;
            if (t == 15) chunkTot = ix;
        }
        __syncthreads();
        int excl = incl - v + wtot[w] + carry;
        if (idx < n) {
            cursor[base + idx]  = gbase + excl;
            inv_deg[base + idx] = 1.0f / fmaxf((float)v, 1.0f);
        }
        carry += chunkTot;
        __syncthreads();
    }
}

__global__ __launch_bounds__(256) void fill_k(EdgeArgs a, int* __restrict__ cursor, int* __restrict__ col) {
    int g = blockIdx.x * 256 + threadIdx.x;
    if (g >= TOTE) return;
    int e = 0;
    while (g >= c_EPRE[e + 1]) e++;
    int k = g - c_EPRE[e];
    int src = a.ei[e][k];
    int dst = a.ei[e][c_ECNT[e] + k];
    int pos = atomicAdd(&cursor[c_CNTOFF[e] + dst], 1);
    col[pos] = c_SRCOFF[e] + src;
}

// ---------------- conversions ----------------
struct XArgs { const float* x[7]; };
__global__ __launch_bounds__(256) void convx_k(XArgs a, unsigned short* __restrict__ hbf) {
    int i4 = blockIdx.x * 256 + threadIdx.x;
    if (i4 >= TOTN * 32) return;           // float4 index
    int idx = i4 * 4;
    int t = 0;
    while (idx >= c_NODEPRE[t + 1] * 128) t++;
    float4 v = *(const float4*)&a.x[t][idx - c_NODEPRE[t] * 128];
    uint2 p;
    p.x = (unsigned)f2bf(v.x) | ((unsigned)f2bf(v.y) << 16);
    p.y = (unsigned)f2bf(v.z) | ((unsigned)f2bf(v.w) << 16);
    *(uint2*)&hbf[idx] = p;
}

// weight slots: 0-6 Wp, 7-48 Wl(l*14+e), 49-90 Wr, 91 Wu, 92 Wv  (93 * 16384 elements)
struct WArgs { const float* Wp; const float* Wl; const float* Wr; const float* Wu; const float* Wv; };
__global__ __launch_bounds__(256) void convw_k(WArgs a, unsigned short* __restrict__ wbf) {
    int i4 = blockIdx.x * 256 + threadIdx.x;
    if (i4 >= 93 * 4096) return;
    int idx = i4 * 4;
    int m = idx >> 14;            // matrix slot
    int i = idx & 16383;
    const float* src;
    if (m < 7)       src = a.Wp + (size_t)m * 16384;
    else if (m < 49) src = a.Wl + (size_t)(m - 7) * 16384;
    else if (m < 91) src = a.Wr + (size_t)(m - 49) * 16384;
    else if (m == 91) src = a.Wu;
    else              src = a.Wv;
    float4 v = *(const float4*)&src[i];
    uint2 p;
    p.x = (unsigned)f2bf(v.x) | ((unsigned)f2bf(v.y) << 16);
    p.y = (unsigned)f2bf(v.z) | ((unsigned)f2bf(v.w) << 16);
    *(uint2*)&wbf[idx] = p;
}

// ---------------- aggregation (mean over neighbors), one wave per dst row, bf16 ----------------
struct AggArgs { int nSlots; int blockPrefix[9]; int cntOff[8]; int aggOff[8]; int rowsN[8]; };

__global__ __launch_bounds__(256) void agg_k(AggArgs a,
        const int* __restrict__ cnt, const int* __restrict__ cursor,
        const float* __restrict__ inv_deg, const int* __restrict__ col,
        const unsigned int* __restrict__ hbu, unsigned int* __restrict__ aggu) {
    int b = blockIdx.x;
    int s = 0;
    while (b >= a.blockPrefix[s + 1]) s++;
    int row = (b - a.blockPrefix[s]) * 4 + (threadIdx.x >> 6);
    if (row >= a.rowsN[s]) return;
    int lane = threadIdx.x & 63;
    int base = a.cntOff[s] + row;
    int nn = cnt[base];
    int rs = cursor[base] - nn;           // cursor==end after fill_k
    float inv = inv_deg[base];
    const int* cp = col + rs;
    float v0 = 0.f, v1 = 0.f;
    int j = 0;
    for (; j + 4 <= nn; j += 4) {
        int c0 = cp[j] * 64, c1 = cp[j+1] * 64, c2 = cp[j+2] * 64, c3 = cp[j+3] * 64;
        unsigned u0 = hbu[c0 + lane], u1 = hbu[c1 + lane], u2 = hbu[c2 + lane], u3 = hbu[c3 + lane];
        v0 += __uint_as_float(u0 << 16) + __uint_as_float(u1 << 16)
            + __uint_as_float(u2 << 16) + __uint_as_float(u3 << 16);
        v1 += __uint_as_float(u0 & 0xFFFF0000u) + __uint_as_float(u1 & 0xFFFF0000u)
            + __uint_as_float(u2 & 0xFFFF0000u) + __uint_as_float(u3 & 0xFFFF0000u);
    }
    for (; j < nn; j++) {
        unsigned u = hbu[cp[j] * 64 + lane];
        v0 += __uint_as_float(u << 16);
        v1 += __uint_as_float(u & 0xFFFF0000u);
    }
    unsigned out = (unsigned)f2bf(v0 * inv) | ((unsigned)f2bf(v1 * inv) << 16);
    aggu[(size_t)(a.aggOff[s] + row) * 64 + lane] = out;
}

// ---------------- MFMA GEMM: out = A1@W1^T (+ A2@W2^T) + bias, optional row-l2norm ----------------
// A,W bf16; accumulate fp32. MODE 0: write bf16 (input proj). MODE 1: l2norm, write fp32.
// MODE 2: l2norm, += fp32. Block = 64 rows x 128 cols; wave = 16 rows x 128 cols.
struct GemmArgs {
    int nSlots; int blockPrefix[9];
    const unsigned short* A1[8]; const unsigned short* A2[8];
    const unsigned short* W1[8]; const unsigned short* W2[8];
    const float* bias[8]; void* out[8];
    int rows[8];
};

template<int MODE, bool TWO>
__global__ __launch_bounds__(256) void gemm_k(GemmArgs g) {
    __shared__ short As[64 * 40];    // 64 rows x 32 k, stride 40 (2-way bank alias = free)
    __shared__ short Ws[128 * 40];   // 128 cols x 32 k, stride 40
    int b = blockIdx.x;
    int s = 0;
    while (b >= g.blockPrefix[s + 1]) s++;
    int rows = g.rows[s];
    int row0 = (b - g.blockPrefix[s]) * 64;
    int t = threadIdx.x;
    int w = t >> 6, lane = t & 63;
    int q = lane >> 4, m15 = lane & 15;

    floatx4 acc[8];
    #pragma unroll
    for (int bb = 0; bb < 8; bb++) acc[bb] = (floatx4){0.f, 0.f, 0.f, 0.f};

    const int MM = TWO ? 2 : 1;
    for (int mm = 0; mm < MM; mm++) {
        const uint4* A4 = (const uint4*)(mm ? g.A2[s] : g.A1[s]);
        const uint4* W4 = (const uint4*)(mm ? g.W2[s] : g.W1[s]);
        for (int k0 = 0; k0 < 128; k0 += 32) {
            __syncthreads();
            {   // A tile: 64 rows x 4 chunks of 8 bf16
                int row = t >> 2, kc = t & 3;
                uint4 v = make_uint4(0u, 0u, 0u, 0u);
                if (row0 + row < rows) v = A4[(size_t)(row0 + row) * 16 + (k0 >> 3) + kc];
                *(uint4*)&As[row * 40 + kc * 8] = v;
            }
            #pragma unroll
            for (int i = 0; i < 2; i++) {   // W tile: 128 cols x 4 chunks
                int idx = t + i * 256;
                int c = idx >> 2, kc = idx & 3;
                uint4 v = W4[(size_t)c * 16 + (k0 >> 3) + kc];
                *(uint4*)&Ws[c * 40 + kc * 8] = v;
            }
            __syncthreads();
            bf16x8 af = __builtin_bit_cast(bf16x8, *(const short8*)&As[(w * 16 + m15) * 40 + q * 8]);
            #pragma unroll
            for (int bb = 0; bb < 8; bb++) {
                bf16x8 bf = __builtin_bit_cast(bf16x8, *(const short8*)&Ws[(bb * 16 + m15) * 40 + q * 8]);
                acc[bb] = __builtin_amdgcn_mfma_f32_16x16x32_bf16(af, bf, acc[bb], 0, 0, 0);
            }
        }
    }

    // epilogue: C/D layout col = lane&15, row = q*4 + reg
    const float* bias = g.bias[s];
    #pragma unroll
    for (int bb = 0; bb < 8; bb++) {
        float bv = bias[bb * 16 + m15];
        #pragma unroll
        for (int reg = 0; reg < 4; reg++) acc[bb][reg] += bv;
    }
    if (MODE != 0) {
        #pragma unroll
        for (int reg = 0; reg < 4; reg++) {
            float ss = 0.f;
            #pragma unroll
            for (int bb = 0; bb < 8; bb++) ss += acc[bb][reg] * acc[bb][reg];
            ss += __shfl_xor(ss, 1);
            ss += __shfl_xor(ss, 2);
            ss += __shfl_xor(ss, 4);
            ss += __shfl_xor(ss, 8);
            float sc = 1.0f / fmaxf(sqrtf(ss), 1e-12f);
            #pragma unroll
            for (int bb = 0; bb < 8; bb++) acc[bb][reg] *= sc;
        }
    }
    int rbase = row0 + w * 16 + q * 4;
    if (MODE == 0) {
        unsigned short* out = (unsigned short*)g.out[s];
        #pragma unroll
        for (int reg = 0; reg < 4; reg++) {
            int r = rbase + reg;
            if (r < rows) {
                unsigned short* o = out + (size_t)r * HID;
                #pragma unroll
                for (int bb = 0; bb < 8; bb++) o[bb * 16 + m15] = f2bf(acc[bb][reg]);
            }
        }
    } else {
        float* out = (float*)g.out[s];
        #pragma unroll
        for (int reg = 0; reg < 4; reg++) {
            int r = rbase + reg;
            if (r < rows) {
                float* o = out + (size_t)r * HID;
                #pragma unroll
                for (int bb = 0; bb < 8; bb++) {
                    if (MODE == 2) o[bb * 16 + m15] += acc[bb][reg];
                    else           o[bb * 16 + m15]  = acc[bb][reg];
                }
            }
        }
    }
}

// ---------------- per-layer update: h = relu(LN(acc/numdst + h)), bf16 in-place ----------------
__global__ __launch_bounds__(256) void update_k(unsigned short* __restrict__ hbf, const float* __restrict__ acc,
                                                const float* __restrict__ ln_g, const float* __restrict__ ln_b, int l) {
    int row = blockIdx.x * 4 + (threadIdx.x >> 6);
    if (row >= TOTN) return;
    int lane = threadIdx.x & 63;
    int t = 0;
    while (row >= c_NODEPRE[t + 1]) t++;
    float invnd = c_INVND[t];
    const float* gg = ln_g + ((size_t)l * 7 + t) * HID;
    const float* bb = ln_b + ((size_t)l * 7 + t) * HID;
    unsigned short* hp = hbf + (size_t)row * HID;
    const float* ap = acc + (size_t)row * HID;
    float x0 = ap[lane] * invnd + bf2f(hp[lane]);
    float x1 = ap[lane + 64] * invnd + bf2f(hp[lane + 64]);
    float s = x0 + x1;
    s += __shfl_xor(s, 1);  s += __shfl_xor(s, 2);  s += __shfl_xor(s, 4);
    s += __shfl_xor(s, 8);  s += __shfl_xor(s, 16); s += __shfl_xor(s, 32);
    float mean = s * (1.0f / 128.0f);
    float d0 = x0 - mean, d1 = x1 - mean;
    float vs = d0 * d0 + d1 * d1;
    vs += __shfl_xor(vs, 1);  vs += __shfl_xor(vs, 2);  vs += __shfl_xor(vs, 4);
    vs += __shfl_xor(vs, 8);  vs += __shfl_xor(vs, 16); vs += __shfl_xor(vs, 32);
    float rstd = rsqrtf(vs * (1.0f / 128.0f) + 1e-5f);
    float y0 = d0 * rstd * gg[lane]      + bb[lane];
    float y1 = d1 * rstd * gg[lane + 64] + bb[lane + 64];
    hp[lane]      = f2bf(fmaxf(y0, 0.f));
    hp[lane + 64] = f2bf(fmaxf(y1, 0.f));
}

// ---------------- host ----------------
extern "C" void kernel_launch(void* const* d_in, const int* in_sizes, int n_in,
                              void* d_out, int out_size, void* d_ws, size_t ws_size,
                              hipStream_t stream) {
    (void)in_sizes; (void)n_in; (void)out_size; (void)ws_size;
    const float* Wp   = (const float*)d_in[21];
    const float* bp   = (const float*)d_in[22];
    const float* Wl   = (const float*)d_in[23];
    const float* bl   = (const float*)d_in[24];
    const float* Wr   = (const float*)d_in[25];
    const float* ln_g = (const float*)d_in[26];
    const float* ln_b = (const float*)d_in[27];
    const float* Wu   = (const float*)d_in[28];
    const float* bu   = (const float*)d_in[29];
    const float* Wv   = (const float*)d_in[30];
    const float* bv   = (const float*)d_in[31];
    float* out = (float*)d_out;

    // d_ws carve (~189 MB)
    float*          acc    = (float*)d_ws;                           // TOTN*128 f32
    unsigned short* h_bf   = (unsigned short*)(acc + (size_t)TOTN * HID); // TOTN*128 bf16
    unsigned short* w_bf   = h_bf + (size_t)TOTN * HID;              // 93*16384 bf16
    int*            cnt    = (int*)(w_bf + (size_t)93 * 16384);      // TOTC
    int*            cursor = cnt + TOTC;                             // TOTC
    float*          invdeg = (float*)(cursor + TOTC);                // TOTC

    // d_out scratch (overwritten by final head GEMM)
    int*            col  = (int*)d_out;                              // TOTE ints
    unsigned short* agg  = (unsigned short*)(col + TOTE);            // <= 74000*128 bf16
    unsigned int*   aggu = (unsigned int*)agg;

    static const int CNTOFF[14] = {0,40000,140000,143000,183000,203000,243000,263000,303000,311000,351000,411000,451000,454000};
    static const int DSTOFF[14] = {100000,0,140000,100000,143000,100000,143000,100000,163000,100000,171000,100000,231000,171000};
    static const int NODEPRE[8] = {0,100000,140000,143000,163000,171000,231000,234000};
    static const int NT[7]      = {100000,40000,3000,20000,8000,60000,3000};

    static const int RN[10]    = {1,1,5,1,2,1,1,1,1,1};
    static const int RM[10]    = {1,1,1,1,2,2,2,2,2,2};
    static const int RE[10][5] = {{1,0,0,0,0},{1,0,0,0,0},{0,2,4,8,12},{10,0,0,0,0},{3,6,0,0,0},{13,0,0,0,0},{5,0,0,0,0},{7,0,0,0,0},{9,0,0,0,0},{11,0,0,0,0}};
    static const int RB[10][5] = {{0,0,0,0,0},{50000,0,0,0,0},{0,0,0,0,0},{0,0,0,0,0},{0,0,0,0,0},{0,0,0,0,0},{0,0,0,0,0},{0,0,0,0,0},{0,0,0,0,0},{0,0,0,0,0}};
    static const int RR[10][5] = {{50000,0,0,0,0},{50000,0,0,0,0},{40000,3000,20000,8000,3000},{60000,0,0,0,0},{40000,20000,0,0,0},{60000,0,0,0,0},{40000,0,0,0,0},{40000,0,0,0,0},{40000,0,0,0,0},{40000,0,0,0,0}};

    EdgeArgs ea;
    for (int e = 0; e < 14; e++) ea.ei[e] = (const int*)d_in[7 + e];

    hipMemsetAsync(cnt, 0, TOTC * sizeof(int), stream);
    count_k<<<(TOTE + 255) / 256, 256, 0, stream>>>(ea, cnt);
    scan_k<<<14, 1024, 0, stream>>>(cnt, cursor, invdeg);
    fill_k<<<(TOTE + 255) / 256, 256, 0, stream>>>(ea, cursor, col);

    {   // conversions
        XArgs xa;
        for (int t = 0; t < 7; t++) xa.x[t] = (const float*)d_in[t];
        convx_k<<<(TOTN * 32 + 255) / 256, 256, 0, stream>>>(xa, h_bf);
        WArgs wa = {Wp, Wl, Wr, Wu, Wv};
        convw_k<<<(93 * 4096 + 255) / 256, 256, 0, stream>>>(wa, w_bf);
    }

    // input projection (in-place bf16): h_bf[t] = x_bf[t] @ Wp[t]^T + bp[t]
    {
        GemmArgs ga; ga.nSlots = 7;
        int pre = 0; ga.blockPrefix[0] = 0;
        for (int t = 0; t < 7; t++) {
            ga.A1[t] = h_bf + (size_t)NODEPRE[t] * HID;
            ga.A2[t] = nullptr;
            ga.W1[t] = w_bf + (size_t)t * 16384;
            ga.W2[t] = nullptr;
            ga.bias[t] = bp + (size_t)t * HID;
            ga.out[t] = h_bf + (size_t)NODEPRE[t] * HID;
            ga.rows[t] = NT[t];
            pre += (NT[t] + 63) / 64;
            ga.blockPrefix[t + 1] = pre;
        }
        ga.blockPrefix[8] = pre;
        gemm_k<0, false><<<pre, 256, 0, stream>>>(ga);
    }

    for (int l = 0; l < 3; l++) {
        for (int r = 0; r < 10; r++) {
            int ns = RN[r];
            AggArgs aa; aa.nSlots = ns;
            GemmArgs ga; ga.nSlots = ns;
            int apre = 0, gpre = 0, aggRows = 0;
            aa.blockPrefix[0] = 0; ga.blockPrefix[0] = 0;
            for (int s = 0; s < ns; s++) {
                int e  = RE[r][s];
                int rb = RB[r][s];
                int nr = RR[r][s];
                aa.cntOff[s] = CNTOFF[e] + rb;
                aa.aggOff[s] = aggRows;
                aa.rowsN[s]  = nr;
                apre += (nr + 3) / 4;  aa.blockPrefix[s + 1] = apre;
                ga.A1[s]  = agg + (size_t)aggRows * HID;
                ga.A2[s]  = h_bf + (size_t)(DSTOFF[e] + rb) * HID;
                ga.W1[s]  = w_bf + (size_t)(7  + l * 14 + e) * 16384;
                ga.W2[s]  = w_bf + (size_t)(49 + l * 14 + e) * 16384;
                ga.bias[s]= bl + ((size_t)l * 14 + e) * HID;
                ga.out[s] = acc + (size_t)(DSTOFF[e] + rb) * HID;
                ga.rows[s]= nr;
                gpre += (nr + 63) / 64; ga.blockPrefix[s + 1] = gpre;
                aggRows += nr;
            }
            for (int s = ns; s < 8; s++) { aa.blockPrefix[s + 1] = apre; ga.blockPrefix[s + 1] = gpre; }
            agg_k<<<apre, 256, 0, stream>>>(aa, cnt, cursor, invdeg, col, (const unsigned int*)h_bf, aggu);
            if (RM[r] == 1) gemm_k<1, true><<<gpre, 256, 0, stream>>>(ga);
            else            gemm_k<2, true><<<gpre, 256, 0, stream>>>(ga);
        }
        update_k<<<(TOTN + 3) / 4, 256, 0, stream>>>(h_bf, acc, ln_g, ln_b, l);
    }

    // heads: l2norm(h @ W^T + b) -> fp32 out (overwrites the col/agg scratch in d_out)
    {
        GemmArgs ga; ga.nSlots = 2;
        ga.blockPrefix[0] = 0;
        ga.A1[0] = h_bf;                        ga.A2[0] = nullptr;
        ga.W1[0] = w_bf + (size_t)91 * 16384;   ga.W2[0] = nullptr;
        ga.bias[0] = bu;                        ga.out[0] = out;
        ga.rows[0] = 100000;
        ga.blockPrefix[1] = (100000 + 63) / 64;
        ga.A1[1] = h_bf + (size_t)100000 * HID; ga.A2[1] = nullptr;
        ga.W1[1] = w_bf + (size_t)92 * 16384;   ga.W2[1] = nullptr;
        ga.bias[1] = bv;                        ga.out[1] = out + (size_t)100000 * HID;
        ga.rows[1] = 40000;
        int tot = ga.blockPrefix[1] + (40000 + 63) / 64;
        for (int s = 2; s <= 8; s++) ga.blockPrefix[s] = tot;
        gemm_k<1, false><<<tot, 256, 0, stream>>>(ga);
    }
}

// Round 4
// 2149.656 us; speedup vs baseline: 2.2203x; 1.1646x over previous
//
#include <hip/hip_runtime.h>
#include <math.h>

// ---------------- compile-time problem constants ----------------
#define TOTE 5400000   // total edges
#define TOTN 234000    // total node rows (all types concatenated)
#define TOTC 514000    // total dst slots over 14 edge types
#define HID  128

// ws carve (~200.7 MB, proven-safe ceiling 245.8 MB):
//   h_bf (59.9MB) + w_bf (3.05MB) + slot (131.6MB) + cnt/cursor/invdeg (6.2MB)
// d_out scratch: col (21.6MB), overwritten by the head GEMM at the end.

typedef __attribute__((ext_vector_type(8))) short short8;
typedef __attribute__((ext_vector_type(8))) __bf16 bf16x8;
typedef __attribute__((ext_vector_type(4))) float floatx4;

__constant__ int c_EPRE[15]   = {0,1000000,2000000,2500000,3000000,3200000,3400000,3600000,3800000,3900000,4000000,4300000,4600000,5000000,5400000};
__constant__ int c_ECNT[14]   = {1000000,1000000,500000,500000,200000,200000,200000,200000,100000,100000,300000,300000,400000,400000};
__constant__ int c_CNTOFF[14] = {0,40000,140000,143000,183000,203000,243000,263000,303000,311000,351000,411000,451000,454000};
__constant__ int c_CNTN[14]   = {40000,100000,3000,40000,20000,40000,20000,40000,8000,40000,60000,40000,3000,60000};
__constant__ int c_SRCOFF[14] = {0,100000,100000,140000,100000,143000,100000,143000,100000,163000,100000,171000,171000,231000};
__constant__ int c_NODEPRE[8] = {0,100000,140000,143000,163000,171000,231000,234000};
__constant__ float c_INVND[7] = {1.0f, 1.0f/6.0f, 1.0f, 0.5f, 1.0f, 0.5f, 1.0f};
// slot ranges feeding each dst node type (for update_k)
__constant__ int c_UPD_NS[7]      = {1,6,1,2,1,2,1};
__constant__ int c_UPD_BASE[7][6] = {
    {40000,0,0,0,0,0},
    {0,143000,203000,263000,311000,411000},
    {140000,0,0,0,0,0},
    {183000,243000,0,0,0,0},
    {303000,0,0,0,0,0},
    {351000,454000,0,0,0,0},
    {451000,0,0,0,0,0}};

static __device__ __forceinline__ unsigned short f2bf(float f) {
    unsigned u = __float_as_uint(f);
    u = u + 0x7FFFu + ((u >> 16) & 1u);
    return (unsigned short)(u >> 16);
}
static __device__ __forceinline__ float bf2f(unsigned short s) {
    return __uint_as_float(((unsigned)s) << 16);
}
static __device__ __forceinline__ unsigned short f2h(float f) {
    _Float16 h = (_Float16)f;
    return __builtin_bit_cast(unsigned short, h);
}
static __device__ __forceinline__ float h2f(unsigned short s) {
    _Float16 h = __builtin_bit_cast(_Float16, s);
    return (float)h;
}

struct EdgeArgs { const int* ei[14]; };

// ---------------- CSR build ----------------
__global__ __launch_bounds__(256) void count_k(EdgeArgs a, int* __restrict__ cnt) {
    int g = blockIdx.x * 256 + threadIdx.x;
    if (g >= TOTE) return;
    int e = 0;
    while (g >= c_EPRE[e + 1]) e++;
    int k = g - c_EPRE[e];
    int dst = a.ei[e][c_ECNT[e] + k];
    atomicAdd(&cnt[c_CNTOFF[e] + dst], 1);
}

__global__ __launch_bounds__(1024) void scan_k(const int* __restrict__ cnt,
                                               int* __restrict__ cursor, float* __restrict__ inv_deg) {
    int e = blockIdx.x;
    int n = c_CNTN[e];
    int base = c_CNTOFF[e];
    int gbase = c_EPRE[e];
    int t = threadIdx.x;
    int lane = t & 63;
    int w = t >> 6;
    __shared__ int wtot[16];
    __shared__ int chunkTot;
    int carry = 0;
    for (int start = 0; start < n; start += 1024) {
        int idx = start + t;
        int v = (idx < n) ? cnt[base + idx] : 0;
        int incl = v;
        #pragma unroll
        for (int d = 1; d < 64; d <<= 1) {
            int o = __shfl_up(incl, d);
            if (lane >= d) incl += o;
        }
        if (lane == 63) wtot[w] = incl;
        __syncthreads();
        if (t < 16) {
            int x = wtot[t];
            int ix = x;
            #pragma unroll
            for (int d = 1; d < 16; d <<= 1) {
                int o = __shfl_up(ix, d);
                if (t >= d) ix += o;
            }
            wtot[t] = ix - x;
            if (t == 15) chunkTot = ix;
        }
        __syncthreads();
        int excl = incl - v + wtot[w] + carry;
        if (idx < n) {
            cursor[base + idx]  = gbase + excl;
            inv_deg[base + idx] = 1.0f / fmaxf((float)v, 1.0f);
        }
        carry += chunkTot;
        __syncthreads();
    }
}

__global__ __launch_bounds__(256) void fill_k(EdgeArgs a, int* __restrict__ cursor, int* __restrict__ col) {
    int g = blockIdx.x * 256 + threadIdx.x;
    if (g >= TOTE) return;
    int e = 0;
    while (g >= c_EPRE[e + 1]) e++;
    int k = g - c_EPRE[e];
    int src = a.ei[e][k];
    int dst = a.ei[e][c_ECNT[e] + k];
    int pos = atomicAdd(&cursor[c_CNTOFF[e] + dst], 1);
    col[pos] = c_SRCOFF[e] + src;
}

// ---------------- conversions ----------------
struct XArgs { const float* x[7]; };
__global__ __launch_bounds__(256) void convx_k(XArgs a, unsigned short* __restrict__ hbf) {
    int i4 = blockIdx.x * 256 + threadIdx.x;
    if (i4 >= TOTN * 32) return;           // float4 index
    int idx = i4 * 4;
    int t = 0;
    while (idx >= c_NODEPRE[t + 1] * 128) t++;
    float4 v = *(const float4*)&a.x[t][idx - c_NODEPRE[t] * 128];
    uint2 p;
    p.x = (unsigned)f2bf(v.x) | ((unsigned)f2bf(v.y) << 16);
    p.y = (unsigned)f2bf(v.z) | ((unsigned)f2bf(v.w) << 16);
    *(uint2*)&hbf[idx] = p;
}

// weight slots: 0-6 Wp, 7-48 Wl(l*14+e), 49-90 Wr, 91 Wu, 92 Wv  (93 * 16384 elements)
struct WArgs { const float* Wp; const float* Wl; const float* Wr; const float* Wu; const float* Wv; };
__global__ __launch_bounds__(256) void convw_k(WArgs a, unsigned short* __restrict__ wbf) {
    int i4 = blockIdx.x * 256 + threadIdx.x;
    if (i4 >= 93 * 4096) return;
    int idx = i4 * 4;
    int m = idx >> 14;
    int i = idx & 16383;
    const float* src;
    if (m < 7)       src = a.Wp + (size_t)m * 16384;
    else if (m < 49) src = a.Wl + (size_t)(m - 7) * 16384;
    else if (m < 91) src = a.Wr + (size_t)(m - 49) * 16384;
    else if (m == 91) src = a.Wu;
    else              src = a.Wv;
    float4 v = *(const float4*)&src[i];
    uint2 p;
    p.x = (unsigned)f2bf(v.x) | ((unsigned)f2bf(v.y) << 16);
    p.y = (unsigned)f2bf(v.z) | ((unsigned)f2bf(v.w) << 16);
    *(uint2*)&wbf[idx] = p;
}

// ---------------- aggregation: one wave per slot, quarter-wave per neighbor ----------------
// lane = 16*q + li; quarter-wave q handles neighbors j+q; lane loads 16B (8 bf16 cols li*8..+8).
// Cross-q reduce via shfl_xor(16/32). Output: bf16 slot row (MFMA A input).
#define ACC8(u) do { \
    v[0] += __uint_as_float((u).x << 16); v[1] += __uint_as_float((u).x & 0xFFFF0000u); \
    v[2] += __uint_as_float((u).y << 16); v[3] += __uint_as_float((u).y & 0xFFFF0000u); \
    v[4] += __uint_as_float((u).z << 16); v[5] += __uint_as_float((u).z & 0xFFFF0000u); \
    v[6] += __uint_as_float((u).w << 16); v[7] += __uint_as_float((u).w & 0xFFFF0000u); } while (0)

__global__ __launch_bounds__(256) void agg_k(
        const int* __restrict__ cnt, const int* __restrict__ cursor,
        const float* __restrict__ inv_deg, const int* __restrict__ col,
        const unsigned short* __restrict__ hbf, unsigned short* __restrict__ slotb) {
    int row = blockIdx.x * 4 + (threadIdx.x >> 6);
    if (row >= TOTC) return;
    int lane = threadIdx.x & 63;
    int q = lane >> 4, li = lane & 15;
    int nn = cnt[row];
    int rs = cursor[row] - nn;           // cursor==end after fill_k
    const int* cp = col + rs;
    float v[8];
    #pragma unroll
    for (int i = 0; i < 8; i++) v[i] = 0.f;
    int j = 0;
    for (; j + 8 <= nn; j += 8) {
        int c0 = cp[j + q] << 7;
        int c1 = cp[j + 4 + q] << 7;
        uint4 u0 = *(const uint4*)&hbf[c0 + li * 8];
        uint4 u1 = *(const uint4*)&hbf[c1 + li * 8];
        ACC8(u0);
        ACC8(u1);
    }
    for (; j < nn; j += 4) {
        if (j + q < nn) {
            int c = cp[j + q] << 7;
            uint4 u = *(const uint4*)&hbf[c + li * 8];
            ACC8(u);
        }
    }
    float inv = inv_deg[row];
    #pragma unroll
    for (int i = 0; i < 8; i++) {
        v[i] += __shfl_xor(v[i], 16);
        v[i] += __shfl_xor(v[i], 32);
        v[i] *= inv;
    }
    if (q == 0) {
        uint4 o;
        o.x = (unsigned)f2bf(v[0]) | ((unsigned)f2bf(v[1]) << 16);
        o.y = (unsigned)f2bf(v[2]) | ((unsigned)f2bf(v[3]) << 16);
        o.z = (unsigned)f2bf(v[4]) | ((unsigned)f2bf(v[5]) << 16);
        o.w = (unsigned)f2bf(v[6]) | ((unsigned)f2bf(v[7]) << 16);
        *(uint4*)&slotb[(size_t)row * HID + li * 8] = o;
    }
}

// ---------------- MFMA GEMM: out = A1@W1^T (+ A2@W2^T) + bias [, l2norm] ----------------
// MODE 0: write bf16 (input proj). MODE 1: l2norm, write f16 (layer slots, in-place over A1).
// MODE 3: l2norm, write fp32 (heads). Block = 64 rows x 128 cols; wave = 16 rows x 128 cols.
struct GemmArgs {
    int blockPrefix[15];
    const unsigned short* A1[14]; const unsigned short* A2[14];
    const unsigned short* W1[14]; const unsigned short* W2[14];
    const float* bias[14]; void* out[14];
    int rows[14];
};

template<int MODE, bool TWO>
__global__ __launch_bounds__(256) void gemm_k(GemmArgs g) {
    __shared__ short As[64 * 40];    // 64 rows x 32 k, stride 40 (2-way bank alias = free)
    __shared__ short Ws[128 * 40];   // 128 cols x 32 k, stride 40
    int b = blockIdx.x;
    int s = 0;
    while (b >= g.blockPrefix[s + 1]) s++;
    int rows = g.rows[s];
    int row0 = (b - g.blockPrefix[s]) * 64;
    int t = threadIdx.x;
    int w = t >> 6, lane = t & 63;
    int q = lane >> 4, m15 = lane & 15;

    floatx4 acc[8];
    #pragma unroll
    for (int bb = 0; bb < 8; bb++) acc[bb] = (floatx4){0.f, 0.f, 0.f, 0.f};

    const int MM = TWO ? 2 : 1;
    for (int mm = 0; mm < MM; mm++) {
        const uint4* A4 = (const uint4*)(mm ? g.A2[s] : g.A1[s]);
        const uint4* W4 = (const uint4*)(mm ? g.W2[s] : g.W1[s]);
        for (int k0 = 0; k0 < 128; k0 += 32) {
            __syncthreads();
            {   // A tile: 64 rows x 4 chunks of 8 bf16
                int row = t >> 2, kc = t & 3;
                uint4 v = make_uint4(0u, 0u, 0u, 0u);
                if (row0 + row < rows) v = A4[(size_t)(row0 + row) * 16 + (k0 >> 3) + kc];
                *(uint4*)&As[row * 40 + kc * 8] = v;
            }
            #pragma unroll
            for (int i = 0; i < 2; i++) {   // W tile: 128 cols x 4 chunks
                int idx = t + i * 256;
                int c = idx >> 2, kc = idx & 3;
                uint4 v = W4[(size_t)c * 16 + (k0 >> 3) + kc];
                *(uint4*)&Ws[c * 40 + kc * 8] = v;
            }
            __syncthreads();
            bf16x8 af = __builtin_bit_cast(bf16x8, *(const short8*)&As[(w * 16 + m15) * 40 + q * 8]);
            #pragma unroll
            for (int bb = 0; bb < 8; bb++) {
                bf16x8 bf = __builtin_bit_cast(bf16x8, *(const short8*)&Ws[(bb * 16 + m15) * 40 + q * 8]);
                acc[bb] = __builtin_amdgcn_mfma_f32_16x16x32_bf16(af, bf, acc[bb], 0, 0, 0);
            }
        }
    }

    // epilogue: C/D layout col = lane&15, row = q*4 + reg
    const float* bias = g.bias[s];
    #pragma unroll
    for (int bb = 0; bb < 8; bb++) {
        float bv = bias[bb * 16 + m15];
        #pragma unroll
        for (int reg = 0; reg < 4; reg++) acc[bb][reg] += bv;
    }
    if (MODE != 0) {
        #pragma unroll
        for (int reg = 0; reg < 4; reg++) {
            float ss = 0.f;
            #pragma unroll
            for (int bb = 0; bb < 8; bb++) ss += acc[bb][reg] * acc[bb][reg];
            ss += __shfl_xor(ss, 1);
            ss += __shfl_xor(ss, 2);
            ss += __shfl_xor(ss, 4);
            ss += __shfl_xor(ss, 8);
            float sc = 1.0f / fmaxf(sqrtf(ss), 1e-12f);
            #pragma unroll
            for (int bb = 0; bb < 8; bb++) acc[bb][reg] *= sc;
        }
    }
    int rbase = row0 + w * 16 + q * 4;
    if (MODE == 3) {
        float* out = (float*)g.out[s];
        #pragma unroll
        for (int reg = 0; reg < 4; reg++) {
            int r = rbase + reg;
            if (r < rows) {
                float* o = out + (size_t)r * HID;
                #pragma unroll
                for (int bb = 0; bb < 8; bb++) o[bb * 16 + m15] = acc[bb][reg];
            }
        }
    } else {
        unsigned short* out = (unsigned short*)g.out[s];
        #pragma unroll
        for (int reg = 0; reg < 4; reg++) {
            int r = rbase + reg;
            if (r < rows) {
                unsigned short* o = out + (size_t)r * HID;
                #pragma unroll
                for (int bb = 0; bb < 8; bb++)
                    o[bb * 16 + m15] = (MODE == 0) ? f2bf(acc[bb][reg]) : f2h(acc[bb][reg]);
            }
        }
    }
}

// ---------------- per-layer update: h = relu(LN(sum(slots)/numdst + h)), bf16 in-place ----------------
__global__ __launch_bounds__(256) void update_k(unsigned short* __restrict__ hbf,
                                                const unsigned short* __restrict__ slotb,
                                                const float* __restrict__ ln_g, const float* __restrict__ ln_b, int l) {
    int row = blockIdx.x * 4 + (threadIdx.x >> 6);
    if (row >= TOTN) return;
    int lane = threadIdx.x & 63;
    int t = 0;
    while (row >= c_NODEPRE[t + 1]) t++;
    int r = row - c_NODEPRE[t];
    int ns = c_UPD_NS[t];
    float s0 = 0.f, s1 = 0.f;
    for (int s = 0; s < ns; s++) {
        const unsigned short* sp = slotb + (size_t)(c_UPD_BASE[t][s] + r) * HID;
        s0 += h2f(sp[lane]);
        s1 += h2f(sp[lane + 64]);
    }
    float invnd = c_INVND[t];
    const float* gg = ln_g + ((size_t)l * 7 + t) * HID;
    const float* bb = ln_b + ((size_t)l * 7 + t) * HID;
    unsigned short* hp = hbf + (size_t)row * HID;
    float x0 = s0 * invnd + bf2f(hp[lane]);
    float x1 = s1 * invnd + bf2f(hp[lane + 64]);
    float s = x0 + x1;
    s += __shfl_xor(s, 1);  s += __shfl_xor(s, 2);  s += __shfl_xor(s, 4);
    s += __shfl_xor(s, 8);  s += __shfl_xor(s, 16); s += __shfl_xor(s, 32);
    float mean = s * (1.0f / 128.0f);
    float d0 = x0 - mean, d1 = x1 - mean;
    float vs = d0 * d0 + d1 * d1;
    vs += __shfl_xor(vs, 1);  vs += __shfl_xor(vs, 2);  vs += __shfl_xor(vs, 4);
    vs += __shfl_xor(vs, 8);  vs += __shfl_xor(vs, 16); vs += __shfl_xor(vs, 32);
    float rstd = rsqrtf(vs * (1.0f / 128.0f) + 1e-5f);
    float y0 = d0 * rstd * gg[lane]      + bb[lane];
    float y1 = d1 * rstd * gg[lane + 64] + bb[lane + 64];
    hp[lane]      = f2bf(fmaxf(y0, 0.f));
    hp[lane + 64] = f2bf(fmaxf(y1, 0.f));
}

// ---------------- host ----------------
extern "C" void kernel_launch(void* const* d_in, const int* in_sizes, int n_in,
                              void* d_out, int out_size, void* d_ws, size_t ws_size,
                              hipStream_t stream) {
    (void)in_sizes; (void)n_in; (void)out_size; (void)ws_size;
    const float* Wp   = (const float*)d_in[21];
    const float* bp   = (const float*)d_in[22];
    const float* Wl   = (const float*)d_in[23];
    const float* bl   = (const float*)d_in[24];
    const float* Wr   = (const float*)d_in[25];
    const float* ln_g = (const float*)d_in[26];
    const float* ln_b = (const float*)d_in[27];
    const float* Wu   = (const float*)d_in[28];
    const float* bu   = (const float*)d_in[29];
    const float* Wv   = (const float*)d_in[30];
    const float* bv   = (const float*)d_in[31];
    float* out = (float*)d_out;

    // d_ws carve (~200.7 MB)
    unsigned short* h_bf   = (unsigned short*)d_ws;                  // TOTN*128 bf16
    unsigned short* w_bf   = h_bf + (size_t)TOTN * HID;              // 93*16384 bf16
    unsigned short* slotb  = w_bf + (size_t)93 * 16384;              // TOTC*128 bf16/f16
    int*            cnt    = (int*)(slotb + (size_t)TOTC * HID);     // TOTC
    int*            cursor = cnt + TOTC;                             // TOTC
    float*          invdeg = (float*)(cursor + TOTC);                // TOTC

    // d_out scratch (overwritten by final head GEMM)
    int* col = (int*)d_out;                                          // TOTE ints

    static const int CNTOFF[14] = {0,40000,140000,143000,183000,203000,243000,263000,303000,311000,351000,411000,451000,454000};
    static const int CNTN[14]   = {40000,100000,3000,40000,20000,40000,20000,40000,8000,40000,60000,40000,3000,60000};
    static const int DSTOFF[14] = {100000,0,140000,100000,143000,100000,143000,100000,163000,100000,171000,100000,231000,171000};
    static const int NODEPRE[8] = {0,100000,140000,143000,163000,171000,231000,234000};
    static const int NT[7]      = {100000,40000,3000,20000,8000,60000,3000};

    EdgeArgs ea;
    for (int e = 0; e < 14; e++) ea.ei[e] = (const int*)d_in[7 + e];

    hipMemsetAsync(cnt, 0, TOTC * sizeof(int), stream);
    count_k<<<(TOTE + 255) / 256, 256, 0, stream>>>(ea, cnt);
    scan_k<<<14, 1024, 0, stream>>>(cnt, cursor, invdeg);
    fill_k<<<(TOTE + 255) / 256, 256, 0, stream>>>(ea, cursor, col);

    {   // conversions
        XArgs xa;
        for (int t = 0; t < 7; t++) xa.x[t] = (const float*)d_in[t];
        convx_k<<<(TOTN * 32 + 255) / 256, 256, 0, stream>>>(xa, h_bf);
        WArgs wa = {Wp, Wl, Wr, Wu, Wv};
        convw_k<<<(93 * 4096 + 255) / 256, 256, 0, stream>>>(wa, w_bf);
    }

    // input projection (in-place bf16): h_bf[t] = x_bf[t] @ Wp[t]^T + bp[t]
    {
        GemmArgs ga;
        int pre = 0; ga.blockPrefix[0] = 0;
        for (int t = 0; t < 7; t++) {
            ga.A1[t] = h_bf + (size_t)NODEPRE[t] * HID;
            ga.A2[t] = nullptr;
            ga.W1[t] = w_bf + (size_t)t * 16384;
            ga.W2[t] = nullptr;
            ga.bias[t] = bp + (size_t)t * HID;
            ga.out[t] = h_bf + (size_t)NODEPRE[t] * HID;
            ga.rows[t] = NT[t];
            pre += (NT[t] + 63) / 64;
            ga.blockPrefix[t + 1] = pre;
        }
        for (int s = 7; s < 14; s++) { ga.blockPrefix[s + 1] = pre; ga.rows[s] = 0; }
        gemm_k<0, false><<<pre, 256, 0, stream>>>(ga);
    }

    // layers: one agg + one gemm + one update dispatch each
    int ggrid;
    GemmArgs gl;   // layer gemm args template (pointers patched per layer)
    {
        int pre = 0; gl.blockPrefix[0] = 0;
        for (int e = 0; e < 14; e++) {
            gl.rows[e] = CNTN[e];
            pre += (CNTN[e] + 63) / 64;
            gl.blockPrefix[e + 1] = pre;
        }
        ggrid = pre;
    }
    for (int l = 0; l < 3; l++) {
        agg_k<<<(TOTC + 3) / 4, 256, 0, stream>>>(cnt, cursor, invdeg, col, h_bf, slotb);
        for (int e = 0; e < 14; e++) {
            gl.A1[e]   = slotb + (size_t)CNTOFF[e] * HID;
            gl.A2[e]   = h_bf + (size_t)DSTOFF[e] * HID;
            gl.W1[e]   = w_bf + (size_t)(7  + l * 14 + e) * 16384;
            gl.W2[e]   = w_bf + (size_t)(49 + l * 14 + e) * 16384;
            gl.bias[e] = bl + ((size_t)l * 14 + e) * HID;
            gl.out[e]  = slotb + (size_t)CNTOFF[e] * HID;   // in-place: bf16 in, f16 out
        }
        gemm_k<1, true><<<ggrid, 256, 0, stream>>>(gl);
        update_k<<<(TOTN + 3) / 4, 256, 0, stream>>>(h_bf, slotb, ln_g, ln_b, l);
    }

    // heads: l2norm(h @ W^T + b) -> fp32 out (overwrites the col scratch in d_out)
    {
        GemmArgs ga;
        ga.blockPrefix[0] = 0;
        ga.A1[0] = h_bf;                        ga.A2[0] = nullptr;
        ga.W1[0] = w_bf + (size_t)91 * 16384;   ga.W2[0] = nullptr;
        ga.bias[0] = bu;                        ga.out[0] = out;
        ga.rows[0] = 100000;
        ga.blockPrefix[1] = (100000 + 63) / 64;
        ga.A1[1] = h_bf + (size_t)100000 * HID; ga.A2[1] = nullptr;
        ga.W1[1] = w_bf + (size_t)92 * 16384;   ga.W2[1] = nullptr;
        ga.bias[1] = bv;                        ga.out[1] = out + (size_t)100000 * HID;
        ga.rows[1] = 40000;
        int tot = ga.blockPrefix[1] + (40000 + 63) / 64;
        for (int s = 2; s < 14; s++) { ga.blockPrefix[s + 1] = tot; ga.rows[s] = 0; }
        ga.blockPrefix[2] = tot;
        gemm_k<3, false><<<tot, 256, 0, stream>>>(ga);
    }
}